// Round 10
// baseline (154.740 us; speedup 1.0000x reference)
//
#include <hip/hip_runtime.h>
#include <hip/hip_bf16.h>
#include <stdint.h>

// RoPE self-attention, bf16-MFMA pipeline.
// B=2 L=2048 D=1024 H=16 DK=64. GEMM1 fuses bias+RoPE+pack (Q,K) and
// bias+transpose (V), LDS-vectorized epilogue. Attention: 32x32x16 MFMA,
// in-register P via cvt_pk+permlane32_swap, split-KV (z=2) with additive
// unnormalized partials (exp2-direct softmax, no max tracking) + merge.
// Q pre-scaled by 0.125*log2(e): scores are exp2-domain.

typedef __attribute__((ext_vector_type(8)))  short bf16x8;   // MFMA A/B frag
typedef __attribute__((ext_vector_type(4)))  float f32x4;    // 16x16 C/D frag
typedef __attribute__((ext_vector_type(16))) float f32x16;   // 32x32 C/D frag
typedef __attribute__((ext_vector_type(4)))  short short4v;
typedef __attribute__((ext_vector_type(4)))  unsigned int u32x4;

#define DEV static __device__ __forceinline__

DEV short f2bf(float f) {            // RNE f32->bf16
  uint32_t u = __builtin_bit_cast(uint32_t, f);
  u += 0x7FFFu + ((u >> 16) & 1u);
  return (short)(u >> 16);
}
DEV float bf2f(short s) {
  return __builtin_bit_cast(float, ((uint32_t)(uint16_t)s) << 16);
}
DEV uint32_t pkbf(float a, float b) { // packed f32x2 -> bf16x2 (v_cvt_pk path)
  __hip_bfloat162 h = __float22bfloat162_rn(make_float2(a, b));
  uint32_t u;
  __builtin_memcpy(&u, &h, 4);
  return u;
}
// v_permlane32_swap_b32 vdst, vsrc: dst.upper <-> src.lower (verified R7)
DEV void pl32swap(uint32_t &dst, uint32_t &src) {
  asm volatile("v_permlane32_swap_b32 %0, %1" : "+v"(dst), "+v"(src));
}

#define AS1 __attribute__((address_space(1)))
#define AS3 __attribute__((address_space(3)))
#define GLOAD_LDS16(gp, lp) \
  __builtin_amdgcn_global_load_lds((const AS1 void*)(gp), (AS3 void*)(lp), 16, 0, 0)

// ---------------------------------------------------------------- f32 -> bf16
__global__ void k_cvt_bf16(const float* __restrict__ in, short* __restrict__ out, int n4) {
  int i = blockIdx.x * 256 + threadIdx.x;
  if (i >= n4) return;
  float4 v = reinterpret_cast<const float4*>(in)[i];
  short4v o = { f2bf(v.x), f2bf(v.y), f2bf(v.z), f2bf(v.w) };
  reinterpret_cast<short4v*>(out)[i] = o;
}

// -------------------------------------------------------------- GEMM template
// body: C128x128 = A[M][K] @ Bt[N][K]^T, BK=64, 4 waves 2x2, m97 structure.
// Lds is one flat 32KB region (As = Lds, Bs = Lds+8192) so epilogues can
// reuse it per-wave after the final barrier.
#define GEMM_BODY(A_, Bt_, K_)                                              \
  __shared__ short Lds[2 * 128 * 64];                                       \
  short* As = Lds;                                                          \
  short* Bs = Lds + 128 * 64;                                               \
  const int tid = threadIdx.x;                                              \
  const int lane = tid & 63;                                                \
  const int wid  = tid >> 6;                                                \
  const int lq = lane & 15, lg = lane >> 4;                                 \
  const int wr = wid >> 1, wc = wid & 1;                                    \
  const int m0 = blockIdx.y * 128;                                          \
  const int n0 = blockIdx.x * 128;                                          \
  f32x4 acc[4][4];                                                          \
  _Pragma("unroll")                                                         \
  for (int i = 0; i < 4; ++i)                                               \
    _Pragma("unroll")                                                       \
    for (int j = 0; j < 4; ++j) acc[i][j] = (f32x4){0.f, 0.f, 0.f, 0.f};    \
  const int KT = (K_) >> 6;                                                 \
  for (int kt = 0; kt < KT; ++kt) {                                         \
    const short* Ag = (A_)  + (size_t)m0 * (K_) + kt * 64;                  \
    const short* Bg = (Bt_) + (size_t)n0 * (K_) + kt * 64;                  \
    _Pragma("unroll")                                                       \
    for (int p = 0; p < 4; ++p) {                                           \
      int f = p * 256 + tid;                                                \
      int row = f >> 3, ce = (f & 7) * 8;                                   \
      GLOAD_LDS16(Ag + (size_t)row * (K_) + ce, As + f * 8);                \
      GLOAD_LDS16(Bg + (size_t)row * (K_) + ce, Bs + f * 8);                \
    }                                                                       \
    asm volatile("s_waitcnt vmcnt(0)" ::: "memory");                        \
    __syncthreads();                                                        \
    _Pragma("unroll")                                                       \
    for (int kk = 0; kk < 2; ++kk) {                                        \
      bf16x8 af[4], bfr[4];                                                 \
      _Pragma("unroll")                                                     \
      for (int i = 0; i < 4; ++i)                                           \
        af[i]  = *reinterpret_cast<const bf16x8*>(                          \
            &As[(wr*64 + i*16 + lq) * 64 + kk*32 + lg*8]);                  \
      _Pragma("unroll")                                                     \
      for (int j = 0; j < 4; ++j)                                           \
        bfr[j] = *reinterpret_cast<const bf16x8*>(                          \
            &Bs[(wc*64 + j*16 + lq) * 64 + kk*32 + lg*8]);                  \
      _Pragma("unroll")                                                     \
      for (int i = 0; i < 4; ++i)                                           \
        _Pragma("unroll")                                                   \
        for (int j = 0; j < 4; ++j)                                         \
          acc[i][j] = __builtin_amdgcn_mfma_f32_16x16x32_bf16(              \
              af[i], bfr[j], acc[i][j], 0, 0, 0);                           \
    }                                                                       \
    __syncthreads();                                                        \
  }

// ---------------- GEMM1: x @ Wqkv^T + b, fused RoPE(Q,K-scaled) + V-transpose
__global__ __launch_bounds__(256) void k_gemm_qkv(
    const short* __restrict__ A, const short* __restrict__ Bt,
    const float* __restrict__ bias,
    const float* __restrict__ cosb, const float* __restrict__ sinb,
    short* __restrict__ Qb, short* __restrict__ Kb, short* __restrict__ Vt)
{
  GEMM_BODY(A, Bt, 1024)

  short* Ep = Lds + wid * 4096;                // per-wave 8KB scratch
  const int cglob = n0 + wc * 64;              // head base col in [0,3072)
  if (cglob < 2048) {                          // ---- Q or K: bias + RoPE
    const bool isq = (cglob < 1024);
    const float QS = isq ? 0.125f * 1.4426950408889634f : 1.0f;
    short* dst = isq ? Qb : Kb;
    const int h = (cglob & 1023) >> 6;
    const float b0 = bias[cglob + lq],      b2 = bias[cglob + 32 + lq];
    const float b1 = bias[cglob + 16 + lq], b3 = bias[cglob + 48 + lq];
    #pragma unroll
    for (int i = 0; i < 4; ++i) {
      #pragma unroll
      for (int r = 0; r < 4; ++r) {
        int lloc = i*16 + lg*4 + r;
        int rg = m0 + wr*64 + lloc;                // global row = b*2048 + l
        float c0 = cosb[(size_t)rg * 32 + lq];
        float s0 = sinb[(size_t)rg * 32 + lq];
        float c1 = cosb[(size_t)rg * 32 + 16 + lq];
        float s1 = sinb[(size_t)rg * 32 + 16 + lq];
        float x1 = acc[i][0][r] + b0, x2 = acc[i][2][r] + b2;   // d = lq
        Ep[lloc*64 + lq]      = f2bf((x1 * c0 - x2 * s0) * QS);
        Ep[lloc*64 + 32 + lq] = f2bf((x1 * s0 + x2 * c0) * QS);
        float y1 = acc[i][1][r] + b1, y2 = acc[i][3][r] + b3;   // d = 16+lq
        Ep[lloc*64 + 16 + lq] = f2bf((y1 * c1 - y2 * s1) * QS);
        Ep[lloc*64 + 48 + lq] = f2bf((y1 * s1 + y2 * c1) * QS);
      }
    }
    #pragma unroll
    for (int p = 0; p < 8; ++p) {
      int f = p * 64 + lane;
      int lloc = f >> 3, d0 = (f & 7) * 8;
      int rg = m0 + wr*64 + lloc;
      int bi = rg >> 11, ll = rg & 2047;
      bf16x8 v = *reinterpret_cast<const bf16x8*>(&Ep[lloc*64 + d0]);
      *reinterpret_cast<bf16x8*>(
          &dst[((size_t)(bi * 16 + h) * 2048 + ll) * 64 + d0]) = v;
    }
  } else {                                     // ---- V: bias + transpose
    const int h = (cglob - 2048) >> 6;
    #pragma unroll
    for (int i = 0; i < 4; ++i) {
      int lloc = i*16 + lg*4;                      // 4 consecutive l
      #pragma unroll
      for (int j = 0; j < 4; ++j) {
        int d = j * 16 + lq;
        float bv = bias[cglob + d];
        short4v pk4 = { f2bf(acc[i][j][0] + bv), f2bf(acc[i][j][1] + bv),
                        f2bf(acc[i][j][2] + bv), f2bf(acc[i][j][3] + bv) };
        *reinterpret_cast<short4v*>(
            &Ep[d*64 + (lloc ^ ((d & 7) << 3))]) = pk4;
      }
    }
    #pragma unroll
    for (int p = 0; p < 8; ++p) {
      int f = p * 64 + lane;
      int d = f >> 3, lc = (f & 7) * 8;
      bf16x8 v = *reinterpret_cast<const bf16x8*>(&Ep[d*64 + lc]);
      int lreal = lc ^ ((d & 7) << 3);
      int rg = m0 + wr*64 + lreal;                 // 8-aligned run of l
      int bi = rg >> 11, ll = rg & 2047;
      *reinterpret_cast<bf16x8*>(
          &Vt[((size_t)(bi * 16 + h) * 64 + d) * 2048 + ll]) = v;
    }
  }
}

// -------------------------------------------- GEMM2: AO @ Wout^T + b, f32 out
__global__ __launch_bounds__(256) void k_gemm_out(
    const short* __restrict__ A, const short* __restrict__ Bt,
    const float* __restrict__ bias, float* __restrict__ C)
{
  GEMM_BODY(A, Bt, 1024)
  const int N = 1024;
  #pragma unroll
  for (int i = 0; i < 4; ++i) {
    int rbase = m0 + wr*64 + i*16 + lg*4;
    #pragma unroll
    for (int j = 0; j < 4; ++j) {
      int col = n0 + wc*64 + j*16 + lq;
      float bv = bias[col];
      #pragma unroll
      for (int r = 0; r < 4; ++r)
        C[(size_t)(rbase + r) * N + col] = acc[i][j][r] + bv;
    }
  }
}

// ------------------------------------------------------------ flash attention
// Split-KV: blockIdx.z selects kv-half (16 tiles of 64). 4 waves/block,
// 32 q-rows/wave (32x32x16 MFMA). K/V staged in LDS, 2-buffer (32KB -> 4
// blocks/CU co-resident with grid 1024 = 4 waves/SIMD). Swapped QK^T,
// exp2-direct softmax (no max tracking => partials over disjoint kv ranges
// are additive), in-register P via cvt_pk+permlane32_swap (T12). Writes
// UNNORMALIZED o (bf16) + l (f32); k_merge combines halves.
__global__ __launch_bounds__(256) void k_attn(
    const short* __restrict__ Q, const short* __restrict__ Kb,
    const short* __restrict__ Vt,
    short* __restrict__ P0, short* __restrict__ P1,
    float* __restrict__ L0, float* __restrict__ L1)
{
  __shared__ short Ks[2][64 * 64];   // 8KB x2, swizzled, rows = kv
  __shared__ short Vs[2][64 * 64];   // 8KB x2, swizzled, rows = d
  const int tid = threadIdx.x;
  const int lane = tid & 63;
  const int wid  = tid >> 6;         // 0..3
  const int Lq = lane & 31;          // q-col / d-col / kv-row
  const int h  = lane >> 5;          // half-select
  const int bh = blockIdx.y;
  const int q0 = blockIdx.x * 128 + wid * 32;
  const int b = bh >> 4, hh = bh & 15;
  const int t0 = blockIdx.z * 16;    // kv-tile base for this half
  short* Pp = blockIdx.z ? P1 : P0;
  float* Lp = blockIdx.z ? L1 : L0;

  const short* Qp = Q  + ((size_t)bh * 2048 + q0 + Lq) * 64;
  const short* Kp = Kb + (size_t)bh * 2048 * 64;
  const short* Vp = Vt + (size_t)bh * 64 * 2048;

  // stage 64x64 bf16 tile: 512 chunks of 16B, 2 per thread (256 threads).
  // LDS linear dest; global source chunk = (c ^ (row&7))  [inverse swizzle]
  #define STAGE_KV(c, t) do {                                              \
    const short* Kg_ = Kp + (size_t)(t) * 64 * 64;                         \
    const short* Vg_ = Vp + (size_t)(t) * 64;                              \
    _Pragma("unroll")                                                      \
    for (int p_ = 0; p_ < 2; ++p_) {                                       \
      int f_ = p_ * 256 + tid;                                             \
      int row_ = f_ >> 3;                                                  \
      int sch_ = (f_ & 7) ^ (row_ & 7);                                    \
      GLOAD_LDS16(Kg_ + row_ * 64 + sch_ * 8,            &Ks[c][f_ * 8]);  \
      GLOAD_LDS16(Vg_ + (size_t)row_ * 2048 + sch_ * 8,  &Vs[c][f_ * 8]);  \
    }                                                                      \
  } while (0)

  // Q B-frags (registers): frag[ks] = Q[q0+Lq][ks*16 + h*8 .. +8]
  bf16x8 qf[4];
  #pragma unroll
  for (int ks = 0; ks < 4; ++ks)
    qf[ks] = *reinterpret_cast<const bf16x8*>(Qp + ks * 16 + h * 8);

  f32x16 o[2];
  #pragma unroll
  for (int nd = 0; nd < 2; ++nd)
    #pragma unroll
    for (int r = 0; r < 16; ++r) o[nd][r] = 0.f;
  float la0 = 0.f, la1 = 0.f, la2 = 0.f, la3 = 0.f;

  STAGE_KV(0, t0);
  asm volatile("s_waitcnt vmcnt(0)" ::: "memory");
  __syncthreads();

  for (int kk2 = 0; kk2 < 16; ++kk2) {
    const int cur = kk2 & 1;
    if (kk2 < 15) STAGE_KV(cur ^ 1, t0 + kk2 + 1);   // prefetch overlaps

    // ---- QK^T: S^T[kv][q], A = K-tile rows (swizzled read), B = qf
    f32x16 s[2];
    #pragma unroll
    for (int mb = 0; mb < 2; ++mb)
      #pragma unroll
      for (int r = 0; r < 16; ++r) s[mb][r] = 0.f;
    #pragma unroll
    for (int ks = 0; ks < 4; ++ks)
      #pragma unroll
      for (int mb = 0; mb < 2; ++mb) {
        bf16x8 kf = *reinterpret_cast<const bf16x8*>(
            &Ks[cur][(mb*32 + Lq) * 64 + (((ks*2 + h) ^ (Lq & 7)) * 8)]);
        s[mb] = __builtin_amdgcn_mfma_f32_32x32x16_bf16(kf, qf[ks], s[mb], 0, 0, 0);
      }
    // ---- softmax (exp2-direct) + pack to bf16 pairs
    uint32_t pk[2][8];
    #pragma unroll
    for (int mb = 0; mb < 2; ++mb)
      #pragma unroll
      for (int j = 0; j < 8; ++j) {
        float pa_ = __builtin_amdgcn_exp2f(s[mb][2*j]);
        float pb_ = __builtin_amdgcn_exp2f(s[mb][2*j + 1]);
        if ((j & 3) == 0) la0 += pa_ + pb_;
        else if ((j & 3) == 1) la1 += pa_ + pb_;
        else if ((j & 3) == 2) la2 += pa_ + pb_;
        else la3 += pa_ + pb_;
        pk[mb][j] = pkbf(pa_, pb_);
      }
    // ---- rebuild PV A-frags in-register + PV
    #pragma unroll
    for (int ks = 0; ks < 4; ++ks) {
      const int mb = ks >> 1, be = (ks & 1) * 4;
      uint32_t w0 = pk[mb][be + 0], w2 = pk[mb][be + 2];
      uint32_t w1 = pk[mb][be + 1], w3 = pk[mb][be + 3];
      pl32swap(w0, w2);
      pl32swap(w1, w3);
      u32x4 paw = { w0, w1, w2, w3 };
      bf16x8 pa = __builtin_bit_cast(bf16x8, paw);
      #pragma unroll
      for (int nd = 0; nd < 2; ++nd) {
        bf16x8 vf = *reinterpret_cast<const bf16x8*>(
            &Vs[cur][(nd*32 + Lq) * 64 + (((ks*2 + h) ^ (Lq & 7)) * 8)]);
        o[nd] = __builtin_amdgcn_mfma_f32_32x32x16_bf16(pa, vf, o[nd], 0, 0, 0);
      }
    }
    asm volatile("s_waitcnt vmcnt(0)" ::: "memory");
    __syncthreads();                 // next tile staged; buffers swap
  }

  // ---- epilogue: partial l + UNNORMALIZED o (merge kernel normalizes)
  float l_part = (la0 + la1) + (la2 + la3);
  l_part += __shfl_xor(l_part, 32, 64);      // both h now hold full partial l
  if (h == 0) Lp[((size_t)bh << 11) + q0 + Lq] = l_part;
  #pragma unroll
  for (int r = 0; r < 16; ++r) {
    int qrow = (r & 3) + 8 * (r >> 2) + 4 * h;
    size_t rowb = ((size_t)b * 2048 + q0 + qrow) * 1024 + hh * 64;
    Pp[rowb + Lq]      = f2bf(o[0][r]);
    Pp[rowb + 32 + Lq] = f2bf(o[1][r]);
  }
  #undef STAGE_KV
}

// ------------------------------------- merge: AO = (P0+P1) / (l0+l1), bf16
__global__ void k_merge(const short* __restrict__ P0, const short* __restrict__ P1,
                        const float* __restrict__ L0, const float* __restrict__ L1,
                        short* __restrict__ AO)
{
  int idx = blockIdx.x * 256 + threadIdx.x;   // 8 elems each; 524288 threads
  int rg = idx >> 7;                 // row 0..4095 = b*2048 + l
  int c0 = (idx & 127) * 8;          // col base (within one 64-col head)
  int bh = ((rg >> 11) << 4) + (c0 >> 6);
  size_t lix = ((size_t)bh << 11) + (rg & 2047);
  float inv = 1.f / (L0[lix] + L1[lix]);
  size_t off = (size_t)rg * 1024 + c0;
  bf16x8 a = *reinterpret_cast<const bf16x8*>(&P0[off]);
  bf16x8 bv = *reinterpret_cast<const bf16x8*>(&P1[off]);
  bf16x8 r;
  #pragma unroll
  for (int j = 0; j < 8; ++j)
    r[j] = f2bf((bf2f(a[j]) + bf2f(bv[j])) * inv);
  *reinterpret_cast<bf16x8*>(&AO[off]) = r;
}

// ----------------------------------------------------------------------------
extern "C" void kernel_launch(void* const* d_in, const int* in_sizes, int n_in,
                              void* d_out, int out_size, void* d_ws, size_t ws_size,
                              hipStream_t stream) {
  (void)in_sizes; (void)n_in; (void)out_size; (void)ws_size;
  const float* x    = (const float*)d_in[0];
  const float* rc   = (const float*)d_in[1];
  const float* rs   = (const float*)d_in[2];
  const float* Wqkv = (const float*)d_in[3];
  const float* bqkv = (const float*)d_in[4];
  const float* Wout = (const float*)d_in[5];
  const float* bout = (const float*)d_in[6];
  float* out = (float*)d_out;

  char* ws = (char*)d_ws;
  short* xb  = (short*)(ws);              // x bf16        [4096][1024]  8.39MB
  short* wqb = (short*)(ws + 8388608);    // Wqkv bf16     [3072][1024]  6.29MB
  short* wob = (short*)(ws + 14680064);   // Wout bf16     [1024][1024]  2.10MB
  short* Qb  = (short*)(ws + 16777216);   // Q roped+scaled[32][2048][64] 8.39MB
  short* Kb  = (short*)(ws + 25165824);   // K roped       [32][2048][64] 8.39MB
  short* Vt  = (short*)(ws + 33554432);   // V transposed  [32][64][2048] 8.39MB
  short* P0  = (short*)(ws + 41943040);   // o partial z=0 [4096][1024]  8.39MB
  short* P1  = (short*)(ws + 50331648);   // o partial z=1 [4096][1024]  8.39MB
  float* L0  = (float*)(ws + 58720256);   // l partial z=0 [32][2048]    0.26MB
  float* L1  = (float*)(ws + 58982400);   // l partial z=1 [32][2048]    0.26MB
                                          // total 59.2MB

  k_cvt_bf16<<<4096, 256, 0, stream>>>(x,    xb,  1048576);
  k_cvt_bf16<<<3072, 256, 0, stream>>>(Wqkv, wqb, 786432);
  k_cvt_bf16<<<1024, 256, 0, stream>>>(Wout, wob, 262144);
  k_gemm_qkv<<<dim3(24, 32), 256, 0, stream>>>(xb, wqb, bqkv, rc, rs, Qb, Kb, Vt);
  k_attn<<<dim3(16, 32, 2), 256, 0, stream>>>(Qb, Kb, Vt, P0, P1, L0, L1);
  k_merge<<<2048, 256, 0, stream>>>(P0, P1, L0, L1, P0);
  k_gemm_out<<<dim3(8, 32), 256, 0, stream>>>(P0, wob, bout, out);
}

// Round 11
// 142.896 us; speedup vs baseline: 1.0829x; 1.0829x over previous
//
#include <hip/hip_runtime.h>
#include <hip/hip_bf16.h>
#include <stdint.h>

// RoPE self-attention, bf16-MFMA pipeline.
// B=2 L=2048 D=1024 H=16 DK=64. GEMM1 fuses bias+RoPE+pack (Q,K) and
// bias+transpose (V), LDS-vectorized epilogue. Attention: 32x32x16 MFMA,
// in-register P via cvt_pk+permlane32_swap, split-KV (z=2) with additive
// unnormalized partials (exp2-direct softmax) + merge. Attn inner loop is
// phase-split (one 32-kv half at a time) + fused exp/pack/PV to keep the
// unified VGPR+AGPR footprint under 128 -> 4 waves/SIMD.
// Q pre-scaled by 0.125*log2(e): scores are exp2-domain.

typedef __attribute__((ext_vector_type(8)))  short bf16x8;   // MFMA A/B frag
typedef __attribute__((ext_vector_type(4)))  float f32x4;    // 16x16 C/D frag
typedef __attribute__((ext_vector_type(16))) float f32x16;   // 32x32 C/D frag
typedef __attribute__((ext_vector_type(4)))  short short4v;
typedef __attribute__((ext_vector_type(4)))  unsigned int u32x4;

#define DEV static __device__ __forceinline__

DEV short f2bf(float f) {            // RNE f32->bf16
  uint32_t u = __builtin_bit_cast(uint32_t, f);
  u += 0x7FFFu + ((u >> 16) & 1u);
  return (short)(u >> 16);
}
DEV float bf2f(short s) {
  return __builtin_bit_cast(float, ((uint32_t)(uint16_t)s) << 16);
}
DEV uint32_t pkbf(float a, float b) { // packed f32x2 -> bf16x2 (v_cvt_pk path)
  __hip_bfloat162 h = __float22bfloat162_rn(make_float2(a, b));
  uint32_t u;
  __builtin_memcpy(&u, &h, 4);
  return u;
}
// v_permlane32_swap_b32 vdst, vsrc: dst.upper <-> src.lower (verified R7)
DEV void pl32swap(uint32_t &dst, uint32_t &src) {
  asm volatile("v_permlane32_swap_b32 %0, %1" : "+v"(dst), "+v"(src));
}

#define AS1 __attribute__((address_space(1)))
#define AS3 __attribute__((address_space(3)))
#define GLOAD_LDS16(gp, lp) \
  __builtin_amdgcn_global_load_lds((const AS1 void*)(gp), (AS3 void*)(lp), 16, 0, 0)

// ---------------------------------------------------------------- f32 -> bf16
__global__ void k_cvt_bf16(const float* __restrict__ in, short* __restrict__ out, int n4) {
  int i = blockIdx.x * 256 + threadIdx.x;
  if (i >= n4) return;
  float4 v = reinterpret_cast<const float4*>(in)[i];
  short4v o = { f2bf(v.x), f2bf(v.y), f2bf(v.z), f2bf(v.w) };
  reinterpret_cast<short4v*>(out)[i] = o;
}

// -------------------------------------------------------------- GEMM template
// body: C128x128 = A[M][K] @ Bt[N][K]^T, BK=64, 4 waves 2x2, m97 structure.
// Lds is one flat 32KB region (As = Lds, Bs = Lds+8192) so epilogues can
// reuse it per-wave after the final barrier.
#define GEMM_BODY(A_, Bt_, K_)                                              \
  __shared__ short Lds[2 * 128 * 64];                                       \
  short* As = Lds;                                                          \
  short* Bs = Lds + 128 * 64;                                               \
  const int tid = threadIdx.x;                                              \
  const int lane = tid & 63;                                                \
  const int wid  = tid >> 6;                                                \
  const int lq = lane & 15, lg = lane >> 4;                                 \
  const int wr = wid >> 1, wc = wid & 1;                                    \
  const int m0 = blockIdx.y * 128;                                          \
  const int n0 = blockIdx.x * 128;                                          \
  f32x4 acc[4][4];                                                          \
  _Pragma("unroll")                                                         \
  for (int i = 0; i < 4; ++i)                                               \
    _Pragma("unroll")                                                       \
    for (int j = 0; j < 4; ++j) acc[i][j] = (f32x4){0.f, 0.f, 0.f, 0.f};    \
  const int KT = (K_) >> 6;                                                 \
  for (int kt = 0; kt < KT; ++kt) {                                         \
    const short* Ag = (A_)  + (size_t)m0 * (K_) + kt * 64;                  \
    const short* Bg = (Bt_) + (size_t)n0 * (K_) + kt * 64;                  \
    _Pragma("unroll")                                                       \
    for (int p = 0; p < 4; ++p) {                                           \
      int f = p * 256 + tid;                                                \
      int row = f >> 3, ce = (f & 7) * 8;                                   \
      GLOAD_LDS16(Ag + (size_t)row * (K_) + ce, As + f * 8);                \
      GLOAD_LDS16(Bg + (size_t)row * (K_) + ce, Bs + f * 8);                \
    }                                                                       \
    asm volatile("s_waitcnt vmcnt(0)" ::: "memory");                        \
    __syncthreads();                                                        \
    _Pragma("unroll")                                                       \
    for (int kk = 0; kk < 2; ++kk) {                                        \
      bf16x8 af[4], bfr[4];                                                 \
      _Pragma("unroll")                                                     \
      for (int i = 0; i < 4; ++i)                                           \
        af[i]  = *reinterpret_cast<const bf16x8*>(                          \
            &As[(wr*64 + i*16 + lq) * 64 + kk*32 + lg*8]);                  \
      _Pragma("unroll")                                                     \
      for (int j = 0; j < 4; ++j)                                           \
        bfr[j] = *reinterpret_cast<const bf16x8*>(                          \
            &Bs[(wc*64 + j*16 + lq) * 64 + kk*32 + lg*8]);                  \
      _Pragma("unroll")                                                     \
      for (int i = 0; i < 4; ++i)                                           \
        _Pragma("unroll")                                                   \
        for (int j = 0; j < 4; ++j)                                         \
          acc[i][j] = __builtin_amdgcn_mfma_f32_16x16x32_bf16(              \
              af[i], bfr[j], acc[i][j], 0, 0, 0);                           \
    }                                                                       \
    __syncthreads();                                                        \
  }

// ---------------- GEMM1: x @ Wqkv^T + b, fused RoPE(Q,K-scaled) + V-transpose
__global__ __launch_bounds__(256) void k_gemm_qkv(
    const short* __restrict__ A, const short* __restrict__ Bt,
    const float* __restrict__ bias,
    const float* __restrict__ cosb, const float* __restrict__ sinb,
    short* __restrict__ Qb, short* __restrict__ Kb, short* __restrict__ Vt)
{
  GEMM_BODY(A, Bt, 1024)

  short* Ep = Lds + wid * 4096;                // per-wave 8KB scratch
  const int cglob = n0 + wc * 64;              // head base col in [0,3072)
  if (cglob < 2048) {                          // ---- Q or K: bias + RoPE
    const bool isq = (cglob < 1024);
    const float QS = isq ? 0.125f * 1.4426950408889634f : 1.0f;
    short* dst = isq ? Qb : Kb;
    const int h = (cglob & 1023) >> 6;
    const float b0 = bias[cglob + lq],      b2 = bias[cglob + 32 + lq];
    const float b1 = bias[cglob + 16 + lq], b3 = bias[cglob + 48 + lq];
    #pragma unroll
    for (int i = 0; i < 4; ++i) {
      #pragma unroll
      for (int r = 0; r < 4; ++r) {
        int lloc = i*16 + lg*4 + r;
        int rg = m0 + wr*64 + lloc;                // global row = b*2048 + l
        float c0 = cosb[(size_t)rg * 32 + lq];
        float s0 = sinb[(size_t)rg * 32 + lq];
        float c1 = cosb[(size_t)rg * 32 + 16 + lq];
        float s1 = sinb[(size_t)rg * 32 + 16 + lq];
        float x1 = acc[i][0][r] + b0, x2 = acc[i][2][r] + b2;   // d = lq
        Ep[lloc*64 + lq]      = f2bf((x1 * c0 - x2 * s0) * QS);
        Ep[lloc*64 + 32 + lq] = f2bf((x1 * s0 + x2 * c0) * QS);
        float y1 = acc[i][1][r] + b1, y2 = acc[i][3][r] + b3;   // d = 16+lq
        Ep[lloc*64 + 16 + lq] = f2bf((y1 * c1 - y2 * s1) * QS);
        Ep[lloc*64 + 48 + lq] = f2bf((y1 * s1 + y2 * c1) * QS);
      }
    }
    #pragma unroll
    for (int p = 0; p < 8; ++p) {
      int f = p * 64 + lane;
      int lloc = f >> 3, d0 = (f & 7) * 8;
      int rg = m0 + wr*64 + lloc;
      int bi = rg >> 11, ll = rg & 2047;
      bf16x8 v = *reinterpret_cast<const bf16x8*>(&Ep[lloc*64 + d0]);
      *reinterpret_cast<bf16x8*>(
          &dst[((size_t)(bi * 16 + h) * 2048 + ll) * 64 + d0]) = v;
    }
  } else {                                     // ---- V: bias + transpose
    const int h = (cglob - 2048) >> 6;
    #pragma unroll
    for (int i = 0; i < 4; ++i) {
      int lloc = i*16 + lg*4;                      // 4 consecutive l
      #pragma unroll
      for (int j = 0; j < 4; ++j) {
        int d = j * 16 + lq;
        float bv = bias[cglob + d];
        short4v pk4 = { f2bf(acc[i][j][0] + bv), f2bf(acc[i][j][1] + bv),
                        f2bf(acc[i][j][2] + bv), f2bf(acc[i][j][3] + bv) };
        *reinterpret_cast<short4v*>(
            &Ep[d*64 + (lloc ^ ((d & 7) << 3))]) = pk4;
      }
    }
    #pragma unroll
    for (int p = 0; p < 8; ++p) {
      int f = p * 64 + lane;
      int d = f >> 3, lc = (f & 7) * 8;
      bf16x8 v = *reinterpret_cast<const bf16x8*>(&Ep[d*64 + lc]);
      int lreal = lc ^ ((d & 7) << 3);
      int rg = m0 + wr*64 + lreal;                 // 8-aligned run of l
      int bi = rg >> 11, ll = rg & 2047;
      *reinterpret_cast<bf16x8*>(
          &Vt[((size_t)(bi * 16 + h) * 64 + d) * 2048 + ll]) = v;
    }
  }
}

// -------------------------------------------- GEMM2: AO @ Wout^T + b, f32 out
__global__ __launch_bounds__(256) void k_gemm_out(
    const short* __restrict__ A, const short* __restrict__ Bt,
    const float* __restrict__ bias, float* __restrict__ C)
{
  GEMM_BODY(A, Bt, 1024)
  const int N = 1024;
  #pragma unroll
  for (int i = 0; i < 4; ++i) {
    int rbase = m0 + wr*64 + i*16 + lg*4;
    #pragma unroll
    for (int j = 0; j < 4; ++j) {
      int col = n0 + wc*64 + j*16 + lq;
      float bv = bias[col];
      #pragma unroll
      for (int r = 0; r < 4; ++r)
        C[(size_t)(rbase + r) * N + col] = acc[i][j][r] + bv;
    }
  }
}

// ------------------------------------------------------------ flash attention
// Split-KV: blockIdx.z selects kv-half (16 tiles of 64). 4 waves/block,
// 32 q-rows/wave (32x32x16 MFMA). K/V staged in LDS, 2-buffer.
// PHASE-SPLIT inner loop: one 32-kv half of S at a time (f32x16 sm, not
// s[2]) with exp/cvt_pk/permlane/PV fused per 16-kv slot -- keeps unified
// VGPR+AGPR footprint < 128 so __launch_bounds__(256,4) gives 4 waves/SIMD
// (R10 showed the old structure capped residency at 2 waves/SIMD).
__global__ __launch_bounds__(256, 4) void k_attn(
    const short* __restrict__ Q, const short* __restrict__ Kb,
    const short* __restrict__ Vt,
    short* __restrict__ P0, short* __restrict__ P1,
    float* __restrict__ L0, float* __restrict__ L1)
{
  __shared__ short Ks[2][64 * 64];   // 8KB x2, swizzled, rows = kv
  __shared__ short Vs[2][64 * 64];   // 8KB x2, swizzled, rows = d
  const int tid = threadIdx.x;
  const int lane = tid & 63;
  const int wid  = tid >> 6;         // 0..3
  const int Lq = lane & 31;          // q-col / d-col / kv-row
  const int h  = lane >> 5;          // half-select
  const int bh = blockIdx.y;
  const int q0 = blockIdx.x * 128 + wid * 32;
  const int b = bh >> 4, hh = bh & 15;
  const int t0 = blockIdx.z * 16;    // kv-tile base for this half
  short* Pp = blockIdx.z ? P1 : P0;
  float* Lp = blockIdx.z ? L1 : L0;

  const short* Qp = Q  + ((size_t)bh * 2048 + q0 + Lq) * 64;
  const short* Kp = Kb + (size_t)bh * 2048 * 64;
  const short* Vp = Vt + (size_t)bh * 64 * 2048;

  // stage 64x64 bf16 tile: 512 chunks of 16B, 2 per thread (256 threads).
  // LDS linear dest; global source chunk = (c ^ (row&7))  [inverse swizzle]
  #define STAGE_KV(c, t) do {                                              \
    const short* Kg_ = Kp + (size_t)(t) * 64 * 64;                         \
    const short* Vg_ = Vp + (size_t)(t) * 64;                              \
    _Pragma("unroll")                                                      \
    for (int p_ = 0; p_ < 2; ++p_) {                                       \
      int f_ = p_ * 256 + tid;                                             \
      int row_ = f_ >> 3;                                                  \
      int sch_ = (f_ & 7) ^ (row_ & 7);                                    \
      GLOAD_LDS16(Kg_ + row_ * 64 + sch_ * 8,            &Ks[c][f_ * 8]);  \
      GLOAD_LDS16(Vg_ + (size_t)row_ * 2048 + sch_ * 8,  &Vs[c][f_ * 8]);  \
    }                                                                      \
  } while (0)

  // Q B-frags (registers): frag[ks] = Q[q0+Lq][ks*16 + h*8 .. +8]
  bf16x8 qf[4];
  #pragma unroll
  for (int ks = 0; ks < 4; ++ks)
    qf[ks] = *reinterpret_cast<const bf16x8*>(Qp + ks * 16 + h * 8);

  f32x16 o[2];
  #pragma unroll
  for (int nd = 0; nd < 2; ++nd)
    #pragma unroll
    for (int r = 0; r < 16; ++r) o[nd][r] = 0.f;
  float la0 = 0.f, la1 = 0.f;

  STAGE_KV(0, t0);
  asm volatile("s_waitcnt vmcnt(0)" ::: "memory");
  __syncthreads();

  for (int kk2 = 0; kk2 < 16; ++kk2) {
    const int cur = kk2 & 1;
    if (kk2 < 15) STAGE_KV(cur ^ 1, t0 + kk2 + 1);   // prefetch overlaps

    #pragma unroll
    for (int mb = 0; mb < 2; ++mb) {       // 32-kv half of the tile
      // ---- QK^T for this half: sm[kv 32..], lane = q-col
      f32x16 sm;
      #pragma unroll
      for (int r = 0; r < 16; ++r) sm[r] = 0.f;
      #pragma unroll
      for (int ks = 0; ks < 4; ++ks) {
        bf16x8 kf = *reinterpret_cast<const bf16x8*>(
            &Ks[cur][(mb*32 + Lq) * 64 + (((ks*2 + h) ^ (Lq & 7)) * 8)]);
        sm = __builtin_amdgcn_mfma_f32_32x32x16_bf16(kf, qf[ks], sm, 0, 0, 0);
      }
      // ---- fused exp2 + pack + permlane + PV, one 16-kv slot at a time
      #pragma unroll
      for (int half = 0; half < 2; ++half) {
        float e0 = __builtin_amdgcn_exp2f(sm[8*half + 0]);
        float e1 = __builtin_amdgcn_exp2f(sm[8*half + 1]);
        float e2 = __builtin_amdgcn_exp2f(sm[8*half + 2]);
        float e3 = __builtin_amdgcn_exp2f(sm[8*half + 3]);
        float e4 = __builtin_amdgcn_exp2f(sm[8*half + 4]);
        float e5 = __builtin_amdgcn_exp2f(sm[8*half + 5]);
        float e6 = __builtin_amdgcn_exp2f(sm[8*half + 6]);
        float e7 = __builtin_amdgcn_exp2f(sm[8*half + 7]);
        la0 += (e0 + e1) + (e4 + e5);
        la1 += (e2 + e3) + (e6 + e7);
        uint32_t w0 = pkbf(e0, e1), w1 = pkbf(e2, e3);
        uint32_t w2 = pkbf(e4, e5), w3 = pkbf(e6, e7);
        pl32swap(w0, w2);
        pl32swap(w1, w3);
        u32x4 paw = { w0, w1, w2, w3 };
        bf16x8 pa = __builtin_bit_cast(bf16x8, paw);
        const int ksl = mb * 2 + half;     // kv-slot 0..3
        #pragma unroll
        for (int nd = 0; nd < 2; ++nd) {
          bf16x8 vf = *reinterpret_cast<const bf16x8*>(
              &Vs[cur][(nd*32 + Lq) * 64 + (((ksl*2 + h) ^ (Lq & 7)) * 8)]);
          o[nd] = __builtin_amdgcn_mfma_f32_32x32x16_bf16(pa, vf, o[nd], 0, 0, 0);
        }
      }
    }
    asm volatile("s_waitcnt vmcnt(0)" ::: "memory");
    __syncthreads();                 // next tile staged; buffers swap
  }

  // ---- epilogue: partial l + UNNORMALIZED o (merge kernel normalizes)
  float l_part = la0 + la1;
  l_part += __shfl_xor(l_part, 32, 64);      // both h now hold full partial l
  if (h == 0) Lp[((size_t)bh << 11) + q0 + Lq] = l_part;
  #pragma unroll
  for (int r = 0; r < 16; ++r) {
    int qrow = (r & 3) + 8 * (r >> 2) + 4 * h;
    size_t rowb = ((size_t)b * 2048 + q0 + qrow) * 1024 + hh * 64;
    Pp[rowb + Lq]      = f2bf(o[0][r]);
    Pp[rowb + 32 + Lq] = f2bf(o[1][r]);
  }
  #undef STAGE_KV
}

// ------------------------------------- merge: AO = (P0+P1) / (l0+l1), bf16
__global__ void k_merge(const short* __restrict__ P0, const short* __restrict__ P1,
                        const float* __restrict__ L0, const float* __restrict__ L1,
                        short* __restrict__ AO)
{
  int idx = blockIdx.x * 256 + threadIdx.x;   // 8 elems each; 524288 threads
  int rg = idx >> 7;                 // row 0..4095 = b*2048 + l
  int c0 = (idx & 127) * 8;          // col base (within one 64-col head)
  int bh = ((rg >> 11) << 4) + (c0 >> 6);
  size_t lix = ((size_t)bh << 11) + (rg & 2047);
  float inv = 1.f / (L0[lix] + L1[lix]);
  size_t off = (size_t)rg * 1024 + c0;
  bf16x8 a = *reinterpret_cast<const bf16x8*>(&P0[off]);
  bf16x8 bv = *reinterpret_cast<const bf16x8*>(&P1[off]);
  bf16x8 r;
  #pragma unroll
  for (int j = 0; j < 8; ++j)
    r[j] = f2bf((bf2f(a[j]) + bf2f(bv[j])) * inv);
  *reinterpret_cast<bf16x8*>(&AO[off]) = r;
}

// ----------------------------------------------------------------------------
extern "C" void kernel_launch(void* const* d_in, const int* in_sizes, int n_in,
                              void* d_out, int out_size, void* d_ws, size_t ws_size,
                              hipStream_t stream) {
  (void)in_sizes; (void)n_in; (void)out_size; (void)ws_size;
  const float* x    = (const float*)d_in[0];
  const float* rc   = (const float*)d_in[1];
  const float* rs   = (const float*)d_in[2];
  const float* Wqkv = (const float*)d_in[3];
  const float* bqkv = (const float*)d_in[4];
  const float* Wout = (const float*)d_in[5];
  const float* bout = (const float*)d_in[6];
  float* out = (float*)d_out;

  char* ws = (char*)d_ws;
  short* xb  = (short*)(ws);              // x bf16        [4096][1024]  8.39MB
  short* wqb = (short*)(ws + 8388608);    // Wqkv bf16     [3072][1024]  6.29MB
  short* wob = (short*)(ws + 14680064);   // Wout bf16     [1024][1024]  2.10MB
  short* Qb  = (short*)(ws + 16777216);   // Q roped+scaled[32][2048][64] 8.39MB
  short* Kb  = (short*)(ws + 25165824);   // K roped       [32][2048][64] 8.39MB
  short* Vt  = (short*)(ws + 33554432);   // V transposed  [32][64][2048] 8.39MB
  short* P0  = (short*)(ws + 41943040);   // o partial z=0 [4096][1024]  8.39MB
  short* P1  = (short*)(ws + 50331648);   // o partial z=1 [4096][1024]  8.39MB
  float* L0  = (float*)(ws + 58720256);   // l partial z=0 [32][2048]    0.26MB
  float* L1  = (float*)(ws + 58982400);   // l partial z=1 [32][2048]    0.26MB
                                          // total 59.2MB

  k_cvt_bf16<<<4096, 256, 0, stream>>>(x,    xb,  1048576);
  k_cvt_bf16<<<3072, 256, 0, stream>>>(Wqkv, wqb, 786432);
  k_cvt_bf16<<<1024, 256, 0, stream>>>(Wout, wob, 262144);
  k_gemm_qkv<<<dim3(24, 32), 256, 0, stream>>>(xb, wqb, bqkv, rc, rs, Qb, Kb, Vt);
  k_attn<<<dim3(16, 32, 2), 256, 0, stream>>>(Qb, Kb, Vt, P0, P1, L0, L1);
  k_merge<<<2048, 256, 0, stream>>>(P0, P1, L0, L1, P0);
  k_gemm_out<<<dim3(8, 32), 256, 0, stream>>>(P0, wob, bout, out);
}

// Round 12
// 132.764 us; speedup vs baseline: 1.1655x; 1.0763x over previous
//
#include <hip/hip_runtime.h>
#include <hip/hip_bf16.h>
#include <stdint.h>

// RoPE self-attention, bf16-MFMA pipeline.
// B=2 L=2048 D=1024 H=16 DK=64. GEMM1 fuses bias+RoPE+pack (Q,K) and
// bias+transpose (V), LDS-vectorized epilogue. GEMM LDS tiles are T2
// XOR-swizzled (pre-swizzled source + swizzled read) -> conflict-free b128.
// Attention: 32x32x16 MFMA, in-register P via cvt_pk+permlane32_swap,
// split-KV (z=2) additive partials + merge, phase-split inner loop for
// 4 waves/SIMD. Q pre-scaled by 0.125*log2(e): scores are exp2-domain.

typedef __attribute__((ext_vector_type(8)))  short bf16x8;   // MFMA A/B frag
typedef __attribute__((ext_vector_type(4)))  float f32x4;    // 16x16 C/D frag
typedef __attribute__((ext_vector_type(16))) float f32x16;   // 32x32 C/D frag
typedef __attribute__((ext_vector_type(4)))  short short4v;
typedef __attribute__((ext_vector_type(4)))  unsigned int u32x4;

#define DEV static __device__ __forceinline__

DEV short f2bf(float f) {            // RNE f32->bf16
  uint32_t u = __builtin_bit_cast(uint32_t, f);
  u += 0x7FFFu + ((u >> 16) & 1u);
  return (short)(u >> 16);
}
DEV float bf2f(short s) {
  return __builtin_bit_cast(float, ((uint32_t)(uint16_t)s) << 16);
}
DEV uint32_t pkbf(float a, float b) { // packed f32x2 -> bf16x2 (v_cvt_pk path)
  __hip_bfloat162 h = __float22bfloat162_rn(make_float2(a, b));
  uint32_t u;
  __builtin_memcpy(&u, &h, 4);
  return u;
}
// v_permlane32_swap_b32 vdst, vsrc: dst.upper <-> src.lower (verified R7)
DEV void pl32swap(uint32_t &dst, uint32_t &src) {
  asm volatile("v_permlane32_swap_b32 %0, %1" : "+v"(dst), "+v"(src));
}

#define AS1 __attribute__((address_space(1)))
#define AS3 __attribute__((address_space(3)))
#define GLOAD_LDS16(gp, lp) \
  __builtin_amdgcn_global_load_lds((const AS1 void*)(gp), (AS3 void*)(lp), 16, 0, 0)

// ---------------------------------------------------------------- f32 -> bf16
__global__ void k_cvt_bf16(const float* __restrict__ in, short* __restrict__ out, int n4) {
  int i = blockIdx.x * 256 + threadIdx.x;
  if (i >= n4) return;
  float4 v = reinterpret_cast<const float4*>(in)[i];
  short4v o = { f2bf(v.x), f2bf(v.y), f2bf(v.z), f2bf(v.w) };
  reinterpret_cast<short4v*>(out)[i] = o;
}

// -------------------------------------------------------------- GEMM template
// body: C128x128 = A[M][K] @ Bt[N][K]^T, BK=64, 4 waves 2x2, m97 structure
// + T2 XOR swizzle: LDS[row][c ^ (row&7)] = global[row][c].  128B rows make
// bank = f(chunk only); swizzle spreads each 16-lane b128 phase across all
// 32 banks at 2 lanes/bank (free, m136). Source pre-swizzle stays within the
// row's 128B cache line -> global coalescing preserved (m173 pattern).
#define GEMM_BODY(A_, Bt_, K_)                                              \
  __shared__ short Lds[2 * 128 * 64];                                       \
  short* As = Lds;                                                          \
  short* Bs = Lds + 128 * 64;                                               \
  const int tid = threadIdx.x;                                              \
  const int lane = tid & 63;                                                \
  const int wid  = tid >> 6;                                                \
  const int lq = lane & 15, lg = lane >> 4;                                 \
  const int wr = wid >> 1, wc = wid & 1;                                    \
  const int m0 = blockIdx.y * 128;                                          \
  const int n0 = blockIdx.x * 128;                                          \
  f32x4 acc[4][4];                                                          \
  _Pragma("unroll")                                                         \
  for (int i = 0; i < 4; ++i)                                               \
    _Pragma("unroll")                                                       \
    for (int j = 0; j < 4; ++j) acc[i][j] = (f32x4){0.f, 0.f, 0.f, 0.f};    \
  const int KT = (K_) >> 6;                                                 \
  for (int kt = 0; kt < KT; ++kt) {                                         \
    const short* Ag = (A_)  + (size_t)m0 * (K_) + kt * 64;                  \
    const short* Bg = (Bt_) + (size_t)n0 * (K_) + kt * 64;                  \
    _Pragma("unroll")                                                       \
    for (int p = 0; p < 4; ++p) {                                           \
      int f = p * 256 + tid;                                                \
      int row = f >> 3;                                                     \
      int sch = (f & 7) ^ (row & 7);            /* inverse-swizzle source */\
      GLOAD_LDS16(Ag + (size_t)row * (K_) + sch * 8, As + f * 8);           \
      GLOAD_LDS16(Bg + (size_t)row * (K_) + sch * 8, Bs + f * 8);           \
    }                                                                       \
    asm volatile("s_waitcnt vmcnt(0)" ::: "memory");                        \
    __syncthreads();                                                        \
    _Pragma("unroll")                                                       \
    for (int kk = 0; kk < 2; ++kk) {                                        \
      bf16x8 af[4], bfr[4];                                                 \
      _Pragma("unroll")                                                     \
      for (int i = 0; i < 4; ++i)                                           \
        af[i]  = *reinterpret_cast<const bf16x8*>(                          \
            &As[(wr*64 + i*16 + lq) * 64 + (((kk*4 + lg) ^ (lq & 7)) * 8)]);\
      _Pragma("unroll")                                                     \
      for (int j = 0; j < 4; ++j)                                           \
        bfr[j] = *reinterpret_cast<const bf16x8*>(                          \
            &Bs[(wc*64 + j*16 + lq) * 64 + (((kk*4 + lg) ^ (lq & 7)) * 8)]);\
      _Pragma("unroll")                                                     \
      for (int i = 0; i < 4; ++i)                                           \
        _Pragma("unroll")                                                   \
        for (int j = 0; j < 4; ++j)                                         \
          acc[i][j] = __builtin_amdgcn_mfma_f32_16x16x32_bf16(              \
              af[i], bfr[j], acc[i][j], 0, 0, 0);                           \
    }                                                                       \
    __syncthreads();                                                        \
  }

// ---------------- GEMM1: x @ Wqkv^T + b, fused RoPE(Q,K-scaled) + V-transpose
__global__ __launch_bounds__(256) void k_gemm_qkv(
    const short* __restrict__ A, const short* __restrict__ Bt,
    const float* __restrict__ bias,
    const float* __restrict__ cosb, const float* __restrict__ sinb,
    short* __restrict__ Qb, short* __restrict__ Kb, short* __restrict__ Vt)
{
  GEMM_BODY(A, Bt, 1024)

  short* Ep = Lds + wid * 4096;                // per-wave 8KB scratch
  const int cglob = n0 + wc * 64;              // head base col in [0,3072)
  if (cglob < 2048) {                          // ---- Q or K: bias + RoPE
    const bool isq = (cglob < 1024);
    const float QS = isq ? 0.125f * 1.4426950408889634f : 1.0f;
    short* dst = isq ? Qb : Kb;
    const int h = (cglob & 1023) >> 6;
    const float b0 = bias[cglob + lq],      b2 = bias[cglob + 32 + lq];
    const float b1 = bias[cglob + 16 + lq], b3 = bias[cglob + 48 + lq];
    #pragma unroll
    for (int i = 0; i < 4; ++i) {
      #pragma unroll
      for (int r = 0; r < 4; ++r) {
        int lloc = i*16 + lg*4 + r;
        int rg = m0 + wr*64 + lloc;                // global row = b*2048 + l
        float c0 = cosb[(size_t)rg * 32 + lq];
        float s0 = sinb[(size_t)rg * 32 + lq];
        float c1 = cosb[(size_t)rg * 32 + 16 + lq];
        float s1 = sinb[(size_t)rg * 32 + 16 + lq];
        float x1 = acc[i][0][r] + b0, x2 = acc[i][2][r] + b2;   // d = lq
        Ep[lloc*64 + lq]      = f2bf((x1 * c0 - x2 * s0) * QS);
        Ep[lloc*64 + 32 + lq] = f2bf((x1 * s0 + x2 * c0) * QS);
        float y1 = acc[i][1][r] + b1, y2 = acc[i][3][r] + b3;   // d = 16+lq
        Ep[lloc*64 + 16 + lq] = f2bf((y1 * c1 - y2 * s1) * QS);
        Ep[lloc*64 + 48 + lq] = f2bf((y1 * s1 + y2 * c1) * QS);
      }
    }
    #pragma unroll
    for (int p = 0; p < 8; ++p) {
      int f = p * 64 + lane;
      int lloc = f >> 3, d0 = (f & 7) * 8;
      int rg = m0 + wr*64 + lloc;
      int bi = rg >> 11, ll = rg & 2047;
      bf16x8 v = *reinterpret_cast<const bf16x8*>(&Ep[lloc*64 + d0]);
      *reinterpret_cast<bf16x8*>(
          &dst[((size_t)(bi * 16 + h) * 2048 + ll) * 64 + d0]) = v;
    }
  } else {                                     // ---- V: bias + transpose
    const int h = (cglob - 2048) >> 6;
    #pragma unroll
    for (int i = 0; i < 4; ++i) {
      int lloc = i*16 + lg*4;                      // 4 consecutive l
      #pragma unroll
      for (int j = 0; j < 4; ++j) {
        int d = j * 16 + lq;
        float bv = bias[cglob + d];
        short4v pk4 = { f2bf(acc[i][j][0] + bv), f2bf(acc[i][j][1] + bv),
                        f2bf(acc[i][j][2] + bv), f2bf(acc[i][j][3] + bv) };
        *reinterpret_cast<short4v*>(
            &Ep[d*64 + (lloc ^ ((d & 7) << 3))]) = pk4;
      }
    }
    #pragma unroll
    for (int p = 0; p < 8; ++p) {
      int f = p * 64 + lane;
      int d = f >> 3, lc = (f & 7) * 8;
      bf16x8 v = *reinterpret_cast<const bf16x8*>(&Ep[d*64 + lc]);
      int lreal = lc ^ ((d & 7) << 3);
      int rg = m0 + wr*64 + lreal;                 // 8-aligned run of l
      int bi = rg >> 11, ll = rg & 2047;
      *reinterpret_cast<bf16x8*>(
          &Vt[((size_t)(bi * 16 + h) * 64 + d) * 2048 + ll]) = v;
    }
  }
}

// -------------------------------------------- GEMM2: AO @ Wout^T + b, f32 out
__global__ __launch_bounds__(256) void k_gemm_out(
    const short* __restrict__ A, const short* __restrict__ Bt,
    const float* __restrict__ bias, float* __restrict__ C)
{
  GEMM_BODY(A, Bt, 1024)
  const int N = 1024;
  #pragma unroll
  for (int i = 0; i < 4; ++i) {
    int rbase = m0 + wr*64 + i*16 + lg*4;
    #pragma unroll
    for (int j = 0; j < 4; ++j) {
      int col = n0 + wc*64 + j*16 + lq;
      float bv = bias[col];
      #pragma unroll
      for (int r = 0; r < 4; ++r)
        C[(size_t)(rbase + r) * N + col] = acc[i][j][r] + bv;
    }
  }
}

// ------------------------------------------------------------ flash attention
// Split-KV: blockIdx.z selects kv-half (16 tiles of 64). 4 waves/block,
// 32 q-rows/wave (32x32x16 MFMA). K/V staged in LDS, 2-buffer.
// PHASE-SPLIT inner loop: one 32-kv half of S at a time (f32x16 sm, not
// s[2]) with exp/cvt_pk/permlane/PV fused per 16-kv slot -- keeps unified
// VGPR+AGPR footprint < 128 so __launch_bounds__(256,4) gives 4 waves/SIMD.
__global__ __launch_bounds__(256, 4) void k_attn(
    const short* __restrict__ Q, const short* __restrict__ Kb,
    const short* __restrict__ Vt,
    short* __restrict__ P0, short* __restrict__ P1,
    float* __restrict__ L0, float* __restrict__ L1)
{
  __shared__ short Ks[2][64 * 64];   // 8KB x2, swizzled, rows = kv
  __shared__ short Vs[2][64 * 64];   // 8KB x2, swizzled, rows = d
  const int tid = threadIdx.x;
  const int lane = tid & 63;
  const int wid  = tid >> 6;         // 0..3
  const int Lq = lane & 31;          // q-col / d-col / kv-row
  const int h  = lane >> 5;          // half-select
  const int bh = blockIdx.y;
  const int q0 = blockIdx.x * 128 + wid * 32;
  const int b = bh >> 4, hh = bh & 15;
  const int t0 = blockIdx.z * 16;    // kv-tile base for this half
  short* Pp = blockIdx.z ? P1 : P0;
  float* Lp = blockIdx.z ? L1 : L0;

  const short* Qp = Q  + ((size_t)bh * 2048 + q0 + Lq) * 64;
  const short* Kp = Kb + (size_t)bh * 2048 * 64;
  const short* Vp = Vt + (size_t)bh * 64 * 2048;

  // stage 64x64 bf16 tile: 512 chunks of 16B, 2 per thread (256 threads).
  // LDS linear dest; global source chunk = (c ^ (row&7))  [inverse swizzle]
  #define STAGE_KV(c, t) do {                                              \
    const short* Kg_ = Kp + (size_t)(t) * 64 * 64;                         \
    const short* Vg_ = Vp + (size_t)(t) * 64;                              \
    _Pragma("unroll")                                                      \
    for (int p_ = 0; p_ < 2; ++p_) {                                       \
      int f_ = p_ * 256 + tid;                                             \
      int row_ = f_ >> 3;                                                  \
      int sch_ = (f_ & 7) ^ (row_ & 7);                                    \
      GLOAD_LDS16(Kg_ + row_ * 64 + sch_ * 8,            &Ks[c][f_ * 8]);  \
      GLOAD_LDS16(Vg_ + (size_t)row_ * 2048 + sch_ * 8,  &Vs[c][f_ * 8]);  \
    }                                                                      \
  } while (0)

  // Q B-frags (registers): frag[ks] = Q[q0+Lq][ks*16 + h*8 .. +8]
  bf16x8 qf[4];
  #pragma unroll
  for (int ks = 0; ks < 4; ++ks)
    qf[ks] = *reinterpret_cast<const bf16x8*>(Qp + ks * 16 + h * 8);

  f32x16 o[2];
  #pragma unroll
  for (int nd = 0; nd < 2; ++nd)
    #pragma unroll
    for (int r = 0; r < 16; ++r) o[nd][r] = 0.f;
  float la0 = 0.f, la1 = 0.f;

  STAGE_KV(0, t0);
  asm volatile("s_waitcnt vmcnt(0)" ::: "memory");
  __syncthreads();

  for (int kk2 = 0; kk2 < 16; ++kk2) {
    const int cur = kk2 & 1;
    if (kk2 < 15) STAGE_KV(cur ^ 1, t0 + kk2 + 1);   // prefetch overlaps

    #pragma unroll
    for (int mb = 0; mb < 2; ++mb) {       // 32-kv half of the tile
      // ---- QK^T for this half: sm[kv 32..], lane = q-col
      f32x16 sm;
      #pragma unroll
      for (int r = 0; r < 16; ++r) sm[r] = 0.f;
      #pragma unroll
      for (int ks = 0; ks < 4; ++ks) {
        bf16x8 kf = *reinterpret_cast<const bf16x8*>(
            &Ks[cur][(mb*32 + Lq) * 64 + (((ks*2 + h) ^ (Lq & 7)) * 8)]);
        sm = __builtin_amdgcn_mfma_f32_32x32x16_bf16(kf, qf[ks], sm, 0, 0, 0);
      }
      // ---- fused exp2 + pack + permlane + PV, one 16-kv slot at a time
      #pragma unroll
      for (int half = 0; half < 2; ++half) {
        float e0 = __builtin_amdgcn_exp2f(sm[8*half + 0]);
        float e1 = __builtin_amdgcn_exp2f(sm[8*half + 1]);
        float e2 = __builtin_amdgcn_exp2f(sm[8*half + 2]);
        float e3 = __builtin_amdgcn_exp2f(sm[8*half + 3]);
        float e4 = __builtin_amdgcn_exp2f(sm[8*half + 4]);
        float e5 = __builtin_amdgcn_exp2f(sm[8*half + 5]);
        float e6 = __builtin_amdgcn_exp2f(sm[8*half + 6]);
        float e7 = __builtin_amdgcn_exp2f(sm[8*half + 7]);
        la0 += (e0 + e1) + (e4 + e5);
        la1 += (e2 + e3) + (e6 + e7);
        uint32_t w0 = pkbf(e0, e1), w1 = pkbf(e2, e3);
        uint32_t w2 = pkbf(e4, e5), w3 = pkbf(e6, e7);
        pl32swap(w0, w2);
        pl32swap(w1, w3);
        u32x4 paw = { w0, w1, w2, w3 };
        bf16x8 pa = __builtin_bit_cast(bf16x8, paw);
        const int ksl = mb * 2 + half;     // kv-slot 0..3
        #pragma unroll
        for (int nd = 0; nd < 2; ++nd) {
          bf16x8 vf = *reinterpret_cast<const bf16x8*>(
              &Vs[cur][(nd*32 + Lq) * 64 + (((ksl*2 + h) ^ (Lq & 7)) * 8)]);
          o[nd] = __builtin_amdgcn_mfma_f32_32x32x16_bf16(pa, vf, o[nd], 0, 0, 0);
        }
      }
    }
    asm volatile("s_waitcnt vmcnt(0)" ::: "memory");
    __syncthreads();                 // next tile staged; buffers swap
  }

  // ---- epilogue: partial l + UNNORMALIZED o (merge kernel normalizes)
  float l_part = la0 + la1;
  l_part += __shfl_xor(l_part, 32, 64);      // both h now hold full partial l
  if (h == 0) Lp[((size_t)bh << 11) + q0 + Lq] = l_part;
  #pragma unroll
  for (int r = 0; r < 16; ++r) {
    int qrow = (r & 3) + 8 * (r >> 2) + 4 * h;
    size_t rowb = ((size_t)b * 2048 + q0 + qrow) * 1024 + hh * 64;
    Pp[rowb + Lq]      = f2bf(o[0][r]);
    Pp[rowb + 32 + Lq] = f2bf(o[1][r]);
  }
  #undef STAGE_KV
}

// ------------------------------------- merge: AO = (P0+P1) / (l0+l1), bf16
__global__ void k_merge(const short* __restrict__ P0, const short* __restrict__ P1,
                        const float* __restrict__ L0, const float* __restrict__ L1,
                        short* __restrict__ AO)
{
  int idx = blockIdx.x * 256 + threadIdx.x;   // 8 elems each; 524288 threads
  int rg = idx >> 7;                 // row 0..4095 = b*2048 + l
  int c0 = (idx & 127) * 8;          // col base (within one 64-col head)
  int bh = ((rg >> 11) << 4) + (c0 >> 6);
  size_t lix = ((size_t)bh << 11) + (rg & 2047);
  float inv = 1.f / (L0[lix] + L1[lix]);
  size_t off = (size_t)rg * 1024 + c0;
  bf16x8 a = *reinterpret_cast<const bf16x8*>(&P0[off]);
  bf16x8 bv = *reinterpret_cast<const bf16x8*>(&P1[off]);
  bf16x8 r;
  #pragma unroll
  for (int j = 0; j < 8; ++j)
    r[j] = f2bf((bf2f(a[j]) + bf2f(bv[j])) * inv);
  *reinterpret_cast<bf16x8*>(&AO[off]) = r;
}

// ----------------------------------------------------------------------------
extern "C" void kernel_launch(void* const* d_in, const int* in_sizes, int n_in,
                              void* d_out, int out_size, void* d_ws, size_t ws_size,
                              hipStream_t stream) {
  (void)in_sizes; (void)n_in; (void)out_size; (void)ws_size;
  const float* x    = (const float*)d_in[0];
  const float* rc   = (const float*)d_in[1];
  const float* rs   = (const float*)d_in[2];
  const float* Wqkv = (const float*)d_in[3];
  const float* bqkv = (const float*)d_in[4];
  const float* Wout = (const float*)d_in[5];
  const float* bout = (const float*)d_in[6];
  float* out = (float*)d_out;

  char* ws = (char*)d_ws;
  short* xb  = (short*)(ws);              // x bf16        [4096][1024]  8.39MB
  short* wqb = (short*)(ws + 8388608);    // Wqkv bf16     [3072][1024]  6.29MB
  short* wob = (short*)(ws + 14680064);   // Wout bf16     [1024][1024]  2.10MB
  short* Qb  = (short*)(ws + 16777216);   // Q roped+scaled[32][2048][64] 8.39MB
  short* Kb  = (short*)(ws + 25165824);   // K roped       [32][2048][64] 8.39MB
  short* Vt  = (short*)(ws + 33554432);   // V transposed  [32][64][2048] 8.39MB
  short* P0  = (short*)(ws + 41943040);   // o partial z=0 [4096][1024]  8.39MB
  short* P1  = (short*)(ws + 50331648);   // o partial z=1 [4096][1024]  8.39MB
  float* L0  = (float*)(ws + 58720256);   // l partial z=0 [32][2048]    0.26MB
  float* L1  = (float*)(ws + 58982400);   // l partial z=1 [32][2048]    0.26MB
                                          // total 59.2MB

  k_cvt_bf16<<<4096, 256, 0, stream>>>(x,    xb,  1048576);
  k_cvt_bf16<<<3072, 256, 0, stream>>>(Wqkv, wqb, 786432);
  k_cvt_bf16<<<1024, 256, 0, stream>>>(Wout, wob, 262144);
  k_gemm_qkv<<<dim3(24, 32), 256, 0, stream>>>(xb, wqb, bqkv, rc, rs, Qb, Kb, Vt);
  k_attn<<<dim3(16, 32, 2), 256, 0, stream>>>(Qb, Kb, Vt, P0, P1, L0, L1);
  k_merge<<<2048, 256, 0, stream>>>(P0, P1, L0, L1, P0);
  k_gemm_out<<<dim3(8, 32), 256, 0, stream>>>(P0, wob, bout, out);
}

// Round 13
// 119.971 us; speedup vs baseline: 1.2898x; 1.1066x over previous
//
#include <hip/hip_runtime.h>
#include <hip/hip_bf16.h>
#include <stdint.h>

// RoPE self-attention, bf16-MFMA pipeline.
// B=2 L=2048 D=1024 H=16 DK=64. GEMM1 fuses bias+RoPE+pack (Q,K) and
// bias+transpose (V), LDS-vectorized epilogue. GEMMs: T2 XOR-swizzled LDS +
// 2-buffer prefetch (stage(t+1) before compute(t), one barrier/iter).
// Attention: 32x32x16 MFMA, in-register P via cvt_pk+permlane32_swap,
// split-KV (z=2) additive partials + merge, phase-split inner loop for
// 4 waves/SIMD. Q pre-scaled by 0.125*log2(e): scores are exp2-domain.

typedef __attribute__((ext_vector_type(8)))  short bf16x8;   // MFMA A/B frag
typedef __attribute__((ext_vector_type(4)))  float f32x4;    // 16x16 C/D frag
typedef __attribute__((ext_vector_type(16))) float f32x16;   // 32x32 C/D frag
typedef __attribute__((ext_vector_type(4)))  short short4v;
typedef __attribute__((ext_vector_type(4)))  unsigned int u32x4;

#define DEV static __device__ __forceinline__

DEV short f2bf(float f) {            // RNE f32->bf16
  uint32_t u = __builtin_bit_cast(uint32_t, f);
  u += 0x7FFFu + ((u >> 16) & 1u);
  return (short)(u >> 16);
}
DEV float bf2f(short s) {
  return __builtin_bit_cast(float, ((uint32_t)(uint16_t)s) << 16);
}
DEV uint32_t pkbf(float a, float b) { // packed f32x2 -> bf16x2 (v_cvt_pk path)
  __hip_bfloat162 h = __float22bfloat162_rn(make_float2(a, b));
  uint32_t u;
  __builtin_memcpy(&u, &h, 4);
  return u;
}
// v_permlane32_swap_b32 vdst, vsrc: dst.upper <-> src.lower (verified R7)
DEV void pl32swap(uint32_t &dst, uint32_t &src) {
  asm volatile("v_permlane32_swap_b32 %0, %1" : "+v"(dst), "+v"(src));
}

#define AS1 __attribute__((address_space(1)))
#define AS3 __attribute__((address_space(3)))
#define GLOAD_LDS16(gp, lp) \
  __builtin_amdgcn_global_load_lds((const AS1 void*)(gp), (AS3 void*)(lp), 16, 0, 0)

// ---------------------------------------------------------------- f32 -> bf16
__global__ void k_cvt_bf16(const float* __restrict__ in, short* __restrict__ out, int n4) {
  int i = blockIdx.x * 256 + threadIdx.x;
  if (i >= n4) return;
  float4 v = reinterpret_cast<const float4*>(in)[i];
  short4v o = { f2bf(v.x), f2bf(v.y), f2bf(v.z), f2bf(v.w) };
  reinterpret_cast<short4v*>(out)[i] = o;
}

// ---------------------------------------------- GEMM tile stage (128x64 x2)
// 1024 16B chunks per tile, 4 per thread. LDS linear dest; global source
// chunk pre-swizzled (c ^ (row&7)) within the row's 128B line (rule #21).
DEV void gemm_stage(const short* Ag, const short* Bg, int K_,
                    short* AsD, short* BsD, int tid) {
  #pragma unroll
  for (int p = 0; p < 4; ++p) {
    int f = p * 256 + tid;
    int row = f >> 3;
    int sch = (f & 7) ^ (row & 7);
    GLOAD_LDS16(Ag + (size_t)row * K_ + sch * 8, AsD + f * 8);
    GLOAD_LDS16(Bg + (size_t)row * K_ + sch * 8, BsD + f * 8);
  }
}

// -------------------------------------------------------------- GEMM template
// body: C128x128 = A[M][K] @ Bt[N][K]^T, BK=64, 4 waves 2x2.
// 2-BUFFER PREFETCH: stage(kt+1) issues BEFORE compute(kt); the single
// __syncthreads per iter (compiler drains vmcnt+lgkm before s_barrier)
// retires it. DMA latency hides under compute -- this kernel runs at
// 2 blocks/CU (unified-file ~188 regs/wave) where implicit inter-block
// overlap can't cover the old issue->vmcnt(0) stall (R12: MfmaUtil 15.6%).
// T2 XOR swizzle on reads: chunk (kk*4+lg) ^ (lq&7) -> 2 lanes/bank (free).
#define GEMM_BODY(A_, Bt_, K_)                                              \
  __shared__ short Lds[4 * 128 * 64];   /* 64KB: buf stride 16384 shorts */ \
  const int tid = threadIdx.x;                                              \
  const int lane = tid & 63;                                                \
  const int wid  = tid >> 6;                                                \
  const int lq = lane & 15, lg = lane >> 4;                                 \
  const int wr = wid >> 1, wc = wid & 1;                                    \
  const int m0 = blockIdx.y * 128;                                          \
  const int n0 = blockIdx.x * 128;                                          \
  f32x4 acc[4][4];                                                          \
  _Pragma("unroll")                                                         \
  for (int i = 0; i < 4; ++i)                                               \
    _Pragma("unroll")                                                       \
    for (int j = 0; j < 4; ++j) acc[i][j] = (f32x4){0.f, 0.f, 0.f, 0.f};    \
  const int KT = (K_) >> 6;                                                 \
  gemm_stage((A_) + (size_t)m0 * (K_), (Bt_) + (size_t)n0 * (K_), (K_),     \
             Lds, Lds + 8192, tid);                                         \
  __syncthreads();                                                          \
  int gbuf = 0;                                                             \
  for (int kt = 0; kt < KT; ++kt) {                                         \
    if (kt + 1 < KT)                                                        \
      gemm_stage((A_)  + (size_t)m0 * (K_) + (kt + 1) * 64,                 \
                 (Bt_) + (size_t)n0 * (K_) + (kt + 1) * 64, (K_),           \
                 Lds + (gbuf ^ 1) * 16384,                                  \
                 Lds + (gbuf ^ 1) * 16384 + 8192, tid);                     \
    const short* As = Lds + gbuf * 16384;                                   \
    const short* Bs = As + 8192;                                            \
    _Pragma("unroll")                                                       \
    for (int kk = 0; kk < 2; ++kk) {                                        \
      bf16x8 af[4], bfr[4];                                                 \
      _Pragma("unroll")                                                     \
      for (int i = 0; i < 4; ++i)                                           \
        af[i]  = *reinterpret_cast<const bf16x8*>(                          \
            &As[(wr*64 + i*16 + lq) * 64 + (((kk*4 + lg) ^ (lq & 7)) * 8)]);\
      _Pragma("unroll")                                                     \
      for (int j = 0; j < 4; ++j)                                           \
        bfr[j] = *reinterpret_cast<const bf16x8*>(                          \
            &Bs[(wc*64 + j*16 + lq) * 64 + (((kk*4 + lg) ^ (lq & 7)) * 8)]);\
      _Pragma("unroll")                                                     \
      for (int i = 0; i < 4; ++i)                                           \
        _Pragma("unroll")                                                   \
        for (int j = 0; j < 4; ++j)                                         \
          acc[i][j] = __builtin_amdgcn_mfma_f32_16x16x32_bf16(              \
              af[i], bfr[j], acc[i][j], 0, 0, 0);                           \
    }                                                                       \
    __syncthreads();                                                        \
    gbuf ^= 1;                                                              \
  }

// ---------------- GEMM1: x @ Wqkv^T + b, fused RoPE(Q,K-scaled) + V-transpose
__global__ __launch_bounds__(256) void k_gemm_qkv(
    const short* __restrict__ A, const short* __restrict__ Bt,
    const float* __restrict__ bias,
    const float* __restrict__ cosb, const float* __restrict__ sinb,
    short* __restrict__ Qb, short* __restrict__ Kb, short* __restrict__ Vt)
{
  GEMM_BODY(A, Bt, 1024)

  short* Ep = Lds + wid * 4096;                // per-wave 8KB scratch
  const int cglob = n0 + wc * 64;              // head base col in [0,3072)
  if (cglob < 2048) {                          // ---- Q or K: bias + RoPE
    const bool isq = (cglob < 1024);
    const float QS = isq ? 0.125f * 1.4426950408889634f : 1.0f;
    short* dst = isq ? Qb : Kb;
    const int h = (cglob & 1023) >> 6;
    const float b0 = bias[cglob + lq],      b2 = bias[cglob + 32 + lq];
    const float b1 = bias[cglob + 16 + lq], b3 = bias[cglob + 48 + lq];
    #pragma unroll
    for (int i = 0; i < 4; ++i) {
      #pragma unroll
      for (int r = 0; r < 4; ++r) {
        int lloc = i*16 + lg*4 + r;
        int rg = m0 + wr*64 + lloc;                // global row = b*2048 + l
        float c0 = cosb[(size_t)rg * 32 + lq];
        float s0 = sinb[(size_t)rg * 32 + lq];
        float c1 = cosb[(size_t)rg * 32 + 16 + lq];
        float s1 = sinb[(size_t)rg * 32 + 16 + lq];
        float x1 = acc[i][0][r] + b0, x2 = acc[i][2][r] + b2;   // d = lq
        Ep[lloc*64 + lq]      = f2bf((x1 * c0 - x2 * s0) * QS);
        Ep[lloc*64 + 32 + lq] = f2bf((x1 * s0 + x2 * c0) * QS);
        float y1 = acc[i][1][r] + b1, y2 = acc[i][3][r] + b3;   // d = 16+lq
        Ep[lloc*64 + 16 + lq] = f2bf((y1 * c1 - y2 * s1) * QS);
        Ep[lloc*64 + 48 + lq] = f2bf((y1 * s1 + y2 * c1) * QS);
      }
    }
    #pragma unroll
    for (int p = 0; p < 8; ++p) {
      int f = p * 64 + lane;
      int lloc = f >> 3, d0 = (f & 7) * 8;
      int rg = m0 + wr*64 + lloc;
      int bi = rg >> 11, ll = rg & 2047;
      bf16x8 v = *reinterpret_cast<const bf16x8*>(&Ep[lloc*64 + d0]);
      *reinterpret_cast<bf16x8*>(
          &dst[((size_t)(bi * 16 + h) * 2048 + ll) * 64 + d0]) = v;
    }
  } else {                                     // ---- V: bias + transpose
    const int h = (cglob - 2048) >> 6;
    #pragma unroll
    for (int i = 0; i < 4; ++i) {
      int lloc = i*16 + lg*4;                      // 4 consecutive l
      #pragma unroll
      for (int j = 0; j < 4; ++j) {
        int d = j * 16 + lq;
        float bv = bias[cglob + d];
        short4v pk4 = { f2bf(acc[i][j][0] + bv), f2bf(acc[i][j][1] + bv),
                        f2bf(acc[i][j][2] + bv), f2bf(acc[i][j][3] + bv) };
        *reinterpret_cast<short4v*>(
            &Ep[d*64 + (lloc ^ ((d & 7) << 3))]) = pk4;
      }
    }
    #pragma unroll
    for (int p = 0; p < 8; ++p) {
      int f = p * 64 + lane;
      int d = f >> 3, lc = (f & 7) * 8;
      bf16x8 v = *reinterpret_cast<const bf16x8*>(&Ep[d*64 + lc]);
      int lreal = lc ^ ((d & 7) << 3);
      int rg = m0 + wr*64 + lreal;                 // 8-aligned run of l
      int bi = rg >> 11, ll = rg & 2047;
      *reinterpret_cast<bf16x8*>(
          &Vt[((size_t)(bi * 16 + h) * 64 + d) * 2048 + ll]) = v;
    }
  }
}

// -------------------------------------------- GEMM2: AO @ Wout^T + b, f32 out
__global__ __launch_bounds__(256) void k_gemm_out(
    const short* __restrict__ A, const short* __restrict__ Bt,
    const float* __restrict__ bias, float* __restrict__ C)
{
  GEMM_BODY(A, Bt, 1024)
  const int N = 1024;
  #pragma unroll
  for (int i = 0; i < 4; ++i) {
    int rbase = m0 + wr*64 + i*16 + lg*4;
    #pragma unroll
    for (int j = 0; j < 4; ++j) {
      int col = n0 + wc*64 + j*16 + lq;
      float bv = bias[col];
      #pragma unroll
      for (int r = 0; r < 4; ++r)
        C[(size_t)(rbase + r) * N + col] = acc[i][j][r] + bv;
    }
  }
}

// ------------------------------------------------------------ flash attention
// Split-KV: blockIdx.z selects kv-half (16 tiles of 64). 4 waves/block,
// 32 q-rows/wave (32x32x16 MFMA). K/V staged in LDS, 2-buffer.
// PHASE-SPLIT inner loop: one 32-kv half of S at a time with exp/cvt_pk/
// permlane/PV fused per 16-kv slot -- keeps unified VGPR+AGPR < 128 so
// __launch_bounds__(256,4) gives 4 waves/SIMD.
__global__ __launch_bounds__(256, 4) void k_attn(
    const short* __restrict__ Q, const short* __restrict__ Kb,
    const short* __restrict__ Vt,
    short* __restrict__ P0, short* __restrict__ P1,
    float* __restrict__ L0, float* __restrict__ L1)
{
  __shared__ short Ks[2][64 * 64];   // 8KB x2, swizzled, rows = kv
  __shared__ short Vs[2][64 * 64];   // 8KB x2, swizzled, rows = d
  const int tid = threadIdx.x;
  const int lane = tid & 63;
  const int wid  = tid >> 6;         // 0..3
  const int Lq = lane & 31;          // q-col / d-col / kv-row
  const int h  = lane >> 5;          // half-select
  const int bh = blockIdx.y;
  const int q0 = blockIdx.x * 128 + wid * 32;
  const int b = bh >> 4, hh = bh & 15;
  const int t0 = blockIdx.z * 16;    // kv-tile base for this half
  short* Pp = blockIdx.z ? P1 : P0;
  float* Lp = blockIdx.z ? L1 : L0;

  const short* Qp = Q  + ((size_t)bh * 2048 + q0 + Lq) * 64;
  const short* Kp = Kb + (size_t)bh * 2048 * 64;
  const short* Vp = Vt + (size_t)bh * 64 * 2048;

  // stage 64x64 bf16 tile: 512 chunks of 16B, 2 per thread (256 threads).
  // LDS linear dest; global source chunk = (c ^ (row&7))  [inverse swizzle]
  #define STAGE_KV(c, t) do {                                              \
    const short* Kg_ = Kp + (size_t)(t) * 64 * 64;                         \
    const short* Vg_ = Vp + (size_t)(t) * 64;                              \
    _Pragma("unroll")                                                      \
    for (int p_ = 0; p_ < 2; ++p_) {                                       \
      int f_ = p_ * 256 + tid;                                             \
      int row_ = f_ >> 3;                                                  \
      int sch_ = (f_ & 7) ^ (row_ & 7);                                    \
      GLOAD_LDS16(Kg_ + row_ * 64 + sch_ * 8,            &Ks[c][f_ * 8]);  \
      GLOAD_LDS16(Vg_ + (size_t)row_ * 2048 + sch_ * 8,  &Vs[c][f_ * 8]);  \
    }                                                                      \
  } while (0)

  // Q B-frags (registers): frag[ks] = Q[q0+Lq][ks*16 + h*8 .. +8]
  bf16x8 qf[4];
  #pragma unroll
  for (int ks = 0; ks < 4; ++ks)
    qf[ks] = *reinterpret_cast<const bf16x8*>(Qp + ks * 16 + h * 8);

  f32x16 o[2];
  #pragma unroll
  for (int nd = 0; nd < 2; ++nd)
    #pragma unroll
    for (int r = 0; r < 16; ++r) o[nd][r] = 0.f;
  float la0 = 0.f, la1 = 0.f;

  STAGE_KV(0, t0);
  asm volatile("s_waitcnt vmcnt(0)" ::: "memory");
  __syncthreads();

  for (int kk2 = 0; kk2 < 16; ++kk2) {
    const int cur = kk2 & 1;
    if (kk2 < 15) STAGE_KV(cur ^ 1, t0 + kk2 + 1);   // prefetch overlaps

    #pragma unroll
    for (int mb = 0; mb < 2; ++mb) {       // 32-kv half of the tile
      // ---- QK^T for this half: sm[kv 32..], lane = q-col
      f32x16 sm;
      #pragma unroll
      for (int r = 0; r < 16; ++r) sm[r] = 0.f;
      #pragma unroll
      for (int ks = 0; ks < 4; ++ks) {
        bf16x8 kf = *reinterpret_cast<const bf16x8*>(
            &Ks[cur][(mb*32 + Lq) * 64 + (((ks*2 + h) ^ (Lq & 7)) * 8)]);
        sm = __builtin_amdgcn_mfma_f32_32x32x16_bf16(kf, qf[ks], sm, 0, 0, 0);
      }
      // ---- fused exp2 + pack + permlane + PV, one 16-kv slot at a time
      #pragma unroll
      for (int half = 0; half < 2; ++half) {
        float e0 = __builtin_amdgcn_exp2f(sm[8*half + 0]);
        float e1 = __builtin_amdgcn_exp2f(sm[8*half + 1]);
        float e2 = __builtin_amdgcn_exp2f(sm[8*half + 2]);
        float e3 = __builtin_amdgcn_exp2f(sm[8*half + 3]);
        float e4 = __builtin_amdgcn_exp2f(sm[8*half + 4]);
        float e5 = __builtin_amdgcn_exp2f(sm[8*half + 5]);
        float e6 = __builtin_amdgcn_exp2f(sm[8*half + 6]);
        float e7 = __builtin_amdgcn_exp2f(sm[8*half + 7]);
        la0 += (e0 + e1) + (e4 + e5);
        la1 += (e2 + e3) + (e6 + e7);
        uint32_t w0 = pkbf(e0, e1), w1 = pkbf(e2, e3);
        uint32_t w2 = pkbf(e4, e5), w3 = pkbf(e6, e7);
        pl32swap(w0, w2);
        pl32swap(w1, w3);
        u32x4 paw = { w0, w1, w2, w3 };
        bf16x8 pa = __builtin_bit_cast(bf16x8, paw);
        const int ksl = mb * 2 + half;     // kv-slot 0..3
        #pragma unroll
        for (int nd = 0; nd < 2; ++nd) {
          bf16x8 vf = *reinterpret_cast<const bf16x8*>(
              &Vs[cur][(nd*32 + Lq) * 64 + (((ksl*2 + h) ^ (Lq & 7)) * 8)]);
          o[nd] = __builtin_amdgcn_mfma_f32_32x32x16_bf16(pa, vf, o[nd], 0, 0, 0);
        }
      }
    }
    asm volatile("s_waitcnt vmcnt(0)" ::: "memory");
    __syncthreads();                 // next tile staged; buffers swap
  }

  // ---- epilogue: partial l + UNNORMALIZED o (merge kernel normalizes)
  float l_part = la0 + la1;
  l_part += __shfl_xor(l_part, 32, 64);      // both h now hold full partial l
  if (h == 0) Lp[((size_t)bh << 11) + q0 + Lq] = l_part;
  #pragma unroll
  for (int r = 0; r < 16; ++r) {
    int qrow = (r & 3) + 8 * (r >> 2) + 4 * h;
    size_t rowb = ((size_t)b * 2048 + q0 + qrow) * 1024 + hh * 64;
    Pp[rowb + Lq]      = f2bf(o[0][r]);
    Pp[rowb + 32 + Lq] = f2bf(o[1][r]);
  }
  #undef STAGE_KV
}

// ------------------------------------- merge: AO = (P0+P1) / (l0+l1), bf16
__global__ void k_merge(const short* __restrict__ P0, const short* __restrict__ P1,
                        const float* __restrict__ L0, const float* __restrict__ L1,
                        short* __restrict__ AO)
{
  int idx = blockIdx.x * 256 + threadIdx.x;   // 8 elems each; 524288 threads
  int rg = idx >> 7;                 // row 0..4095 = b*2048 + l
  int c0 = (idx & 127) * 8;          // col base (within one 64-col head)
  int bh = ((rg >> 11) << 4) + (c0 >> 6);
  size_t lix = ((size_t)bh << 11) + (rg & 2047);
  float inv = 1.f / (L0[lix] + L1[lix]);
  size_t off = (size_t)rg * 1024 + c0;
  bf16x8 a = *reinterpret_cast<const bf16x8*>(&P0[off]);
  bf16x8 bv = *reinterpret_cast<const bf16x8*>(&P1[off]);
  bf16x8 r;
  #pragma unroll
  for (int j = 0; j < 8; ++j)
    r[j] = f2bf((bf2f(a[j]) + bf2f(bv[j])) * inv);
  *reinterpret_cast<bf16x8*>(&AO[off]) = r;
}

// ----------------------------------------------------------------------------
extern "C" void kernel_launch(void* const* d_in, const int* in_sizes, int n_in,
                              void* d_out, int out_size, void* d_ws, size_t ws_size,
                              hipStream_t stream) {
  (void)in_sizes; (void)n_in; (void)out_size; (void)ws_size;
  const float* x    = (const float*)d_in[0];
  const float* rc   = (const float*)d_in[1];
  const float* rs   = (const float*)d_in[2];
  const float* Wqkv = (const float*)d_in[3];
  const float* bqkv = (const float*)d_in[4];
  const float* Wout = (const float*)d_in[5];
  const float* bout = (const float*)d_in[6];
  float* out = (float*)d_out;

  char* ws = (char*)d_ws;
  short* xb  = (short*)(ws);              // x bf16        [4096][1024]  8.39MB
  short* wqb = (short*)(ws + 8388608);    // Wqkv bf16     [3072][1024]  6.29MB
  short* wob = (short*)(ws + 14680064);   // Wout bf16     [1024][1024]  2.10MB
  short* Qb  = (short*)(ws + 16777216);   // Q roped+scaled[32][2048][64] 8.39MB
  short* Kb  = (short*)(ws + 25165824);   // K roped       [32][2048][64] 8.39MB
  short* Vt  = (short*)(ws + 33554432);   // V transposed  [32][64][2048] 8.39MB
  short* P0  = (short*)(ws + 41943040);   // o partial z=0 [4096][1024]  8.39MB
  short* P1  = (short*)(ws + 50331648);   // o partial z=1 [4096][1024]  8.39MB
  float* L0  = (float*)(ws + 58720256);   // l partial z=0 [32][2048]    0.26MB
  float* L1  = (float*)(ws + 58982400);   // l partial z=1 [32][2048]    0.26MB
                                          // total 59.2MB

  k_cvt_bf16<<<4096, 256, 0, stream>>>(x,    xb,  1048576);
  k_cvt_bf16<<<3072, 256, 0, stream>>>(Wqkv, wqb, 786432);
  k_cvt_bf16<<<1024, 256, 0, stream>>>(Wout, wob, 262144);
  k_gemm_qkv<<<dim3(24, 32), 256, 0, stream>>>(xb, wqb, bqkv, rc, rs, Qb, Kb, Vt);
  k_attn<<<dim3(16, 32, 2), 256, 0, stream>>>(Qb, Kb, Vt, P0, P1, L0, L1);
  k_merge<<<2048, 256, 0, stream>>>(P0, P1, L0, L1, P0);
  k_gemm_out<<<dim3(8, 32), 256, 0, stream>>>(P0, wob, bout, out);
}